// Round 2
// baseline (8607.128 us; speedup 1.0000x reference)
//
#include <hip/hip_runtime.h>
#include <hip/hip_bf16.h>

// CGCNN-PyG forward. Sizes fixed per reference.
#define N_ATOMS 50000
#define N_EDGES 1200000
#define FA 92
#define FB 41
#define DD 64
#define HH 128
#define LL 3
#define GG 1024
#define NBATCH (N_EDGES / 64)   // 18750, exact

// stable softplus matching jax.nn.softplus = max(x,0) + log1p(exp(-|x|))
__device__ __forceinline__ float sp_f(float x) {
  float ax = fabsf(x);
  float e  = __expf(-ax);
  float l  = __logf(1.f + e);
  return fmaxf(x, 0.f) + l;
}

// Swizzled panel offset (words) for P[k][e], 64x64 fp32, row stride 68.
// chunk-XOR by S(k)=(k^(k>>3))&7 + half-chunk rotation R(k)=(k>>3)&1 keeps:
//  - compute reads (uniform k, lane-varying e-chunk): 2-way max
//  - column sweeps (fixed e, lane=k): 2-way
//  - result writes (lane (er,dc) -> rows 8dc+j): 8-way (b128 floor)
__device__ __forceinline__ int poff(int k, int e) {
  int s = (k ^ (k >> 3)) & 7;
  int r = (k >> 3) & 1;
  return k * 68 + ((((e >> 3) ^ s) << 3) + (r << 2)) + (e & 7);
}

// C[8e][8d] += A(panel) @ W(global k-major [k][64]); acc init = bias or 0
template<bool INITBIAS>
__device__ __forceinline__ void mv64(const float* __restrict__ T,
                                     const float* __restrict__ Wk,
                                     const float (&bias8)[8],
                                     int er, int dc, float (&acc)[8][8]) {
#pragma unroll
  for (int i = 0; i < 8; ++i)
#pragma unroll
    for (int j = 0; j < 8; ++j) acc[i][j] = INITBIAS ? bias8[j] : 0.f;
#pragma unroll 4
  for (int k = 0; k < 64; ++k) {
    const float4 a0 = *(const float4*)&T[poff(k, er * 8)];
    const float4 a1 = *(const float4*)&T[poff(k, er * 8 + 4)];
    const float4 w0 = *(const float4*)&Wk[k * DD + dc * 8];
    const float4 w1 = *(const float4*)&Wk[k * DD + dc * 8 + 4];
    const float A[8] = {a0.x, a0.y, a0.z, a0.w, a1.x, a1.y, a1.z, a1.w};
    const float W[8] = {w0.x, w0.y, w0.z, w0.w, w1.x, w1.y, w1.z, w1.w};
#pragma unroll
    for (int i = 0; i < 8; ++i)
#pragma unroll
      for (int j = 0; j < 8; ++j) acc[i][j] = fmaf(A[i], W[j], acc[i][j]);
  }
}

// write C[8e][8d] into panel as P'[d][e] (input of next matvec)
__device__ __forceinline__ void wr_panel(float* __restrict__ T, int er, int dc,
                                         const float (&acc)[8][8]) {
#pragma unroll
  for (int j = 0; j < 8; ++j) {
    int d = dc * 8 + j;
    *(float4*)&T[poff(d, er * 8)]     = make_float4(acc[0][j], acc[1][j], acc[2][j], acc[3][j]);
    *(float4*)&T[poff(d, er * 8 + 4)] = make_float4(acc[4][j], acc[5][j], acc[6][j], acc[7][j]);
  }
}

// h = x @ atom_W + atom_b   [N,92]->[N,64]
__global__ __launch_bounds__(256)
void atom_embed_kernel(const float* __restrict__ x, const float* __restrict__ W,
                       const float* __restrict__ b, float* __restrict__ h) {
  int n = blockIdx.x * 4 + (threadIdx.x >> 6);
  int lane = threadIdx.x & 63;
  if (n >= N_ATOMS) return;
  float acc = b[lane];
  const float* xr = x + (size_t)n * FA;
#pragma unroll
  for (int k = 0; k < FA; ++k) acc = fmaf(xr[k], W[k * DD + lane], acc);
  h[(size_t)n * DD + lane] = acc;
}

// e = edge_attr @ bond_W + bond_b   [E,41]->[E,64]
__global__ __launch_bounds__(256)
void bond_embed_kernel(const float* __restrict__ ea, const float* __restrict__ W,
                       const float* __restrict__ b, float* __restrict__ e) {
  int eg = blockIdx.x * 4 + (threadIdx.x >> 6);
  int lane = threadIdx.x & 63;
  if (eg >= N_EDGES) return;
  float acc = b[lane];
  const float* er = ea + (size_t)eg * FB;
#pragma unroll
  for (int k = 0; k < FB; ++k) acc = fmaf(er[k], W[k * DD + lane], acc);
  e[(size_t)eg * DD + lane] = acc;
}

// Ha = h@Wa, Hb = h@Wb, Hc = h@Wc  (node-side precompute of concat-matmul parts)
__global__ __launch_bounds__(256)
void node_pre_kernel(const float* __restrict__ h, const float* __restrict__ Wa,
                     const float* __restrict__ Wb, const float* __restrict__ Wc,
                     float* __restrict__ Ha, float* __restrict__ Hb, float* __restrict__ Hc) {
  int n = blockIdx.x * 4 + (threadIdx.x >> 6);
  int lane = threadIdx.x & 63;
  if (n >= N_ATOMS) return;
  float a = 0.f, bb = 0.f, c = 0.f;
  const float* hr = h + (size_t)n * DD;
#pragma unroll
  for (int k = 0; k < DD; ++k) {
    float hv = hr[k];
    a  = fmaf(hv, Wa[k * DD + lane], a);
    bb = fmaf(hv, Wb[k * DD + lane], bb);
    c  = fmaf(hv, Wc[k * DD + lane], c);
  }
  Ha[(size_t)n * DD + lane] = a;
  Hb[(size_t)n * DD + lane] = bb;
  Hc[(size_t)n * DD + lane] = c;
}

// Fused per-edge layer, register-tiled. Per 64-edge batch:
//   stage e^T panel -> mv(W1c) -> [+Ha[r]+Hb[c]+b1, sp] -> mv(W2)+b2 = e_new
//   -> mv(W1b) -> [+Hc[r]+nb1, sp] -> mv(nW2)+nb2 = msg -> atomic scatter.
// Weights stream from global (L1-resident, lane-varying dwordx4).
__global__ __launch_bounds__(256, 2)
void edge_layer_kernel(const float* __restrict__ Ha, const float* __restrict__ Hb,
                       const float* __restrict__ Hc, float* __restrict__ e_g,
                       const int* __restrict__ row_g, const int* __restrict__ col_g,
                       const float* __restrict__ W1c, const float* __restrict__ W2,
                       const float* __restrict__ W1b, const float* __restrict__ nW2,
                       const float* __restrict__ b1, const float* __restrict__ b2,
                       const float* __restrict__ nb1, const float* __restrict__ nb2,
                       float* __restrict__ hnew, int nbatch) {
  __shared__ float lds[4][64 * 68];      // 69,632 B -> 2 blocks/CU
  const int wid = threadIdx.x >> 6;
  const int lane = threadIdx.x & 63;
  const int er = lane >> 3, dc = lane & 7, dc8 = dc * 8;
  float* T = lds[wid];
  float b1v[8], b2v[8], nb1v[8], nb2v[8];
#pragma unroll
  for (int j = 0; j < 8; ++j) {
    b1v[j] = b1[dc8 + j];  b2v[j] = b2[dc8 + j];
    nb1v[j] = nb1[dc8 + j]; nb2v[j] = nb2[dc8 + j];
  }
  const int w0 = blockIdx.x * 4 + wid;
  const int nw = gridDim.x * 4;
  const int Sl = (lane ^ (lane >> 3)) & 7;          // stage-in swizzle consts
  const int rowbase = lane * 68 + (((lane >> 3) & 1) << 2);

  for (int b = w0; b < nbatch; b += nw) {
    const int ebase = b * 64;
    int r_[8], c_[8];
#pragma unroll
    for (int i = 0; i < 8; ++i) {
      r_[i] = row_g[ebase + er * 8 + i];
      c_[i] = col_g[ebase + er * 8 + i];
    }
    // stage e^T into panel: lane = channel, column writes (2-way max)
#pragma unroll 8
    for (int el = 0; el < 64; ++el) {
      float v = e_g[(size_t)(ebase + el) * DD + lane];
      T[rowbase + ((((el >> 3) ^ Sl) << 3) + (el & 7))] = v;
    }

    float acc[8][8];
    mv64<false>(T, W1c, b1v, er, dc, acc);          // t1 partial (bias unused)
    // elementwise 1: + Ha[row] + Hb[col] + b1, softplus (all in regs)
#pragma unroll
    for (int i = 0; i < 8; ++i) {
      const float4 ha0 = *(const float4*)&Ha[(size_t)r_[i] * DD + dc8];
      const float4 ha1 = *(const float4*)&Ha[(size_t)r_[i] * DD + dc8 + 4];
      const float4 hb0 = *(const float4*)&Hb[(size_t)c_[i] * DD + dc8];
      const float4 hb1 = *(const float4*)&Hb[(size_t)c_[i] * DD + dc8 + 4];
      const float ga[8] = {ha0.x, ha0.y, ha0.z, ha0.w, ha1.x, ha1.y, ha1.z, ha1.w};
      const float gb[8] = {hb0.x, hb0.y, hb0.z, hb0.w, hb1.x, hb1.y, hb1.z, hb1.w};
#pragma unroll
      for (int j = 0; j < 8; ++j)
        acc[i][j] = sp_f(acc[i][j] + ga[j] + gb[j] + b1v[j]);
    }
    wr_panel(T, er, dc, acc);
    mv64<true>(T, W2, b2v, er, dc, acc);            // e_new
    // write e_new to global (in place) + panel (input of mv3)
#pragma unroll
    for (int i = 0; i < 8; ++i) {
      *(float4*)&e_g[(size_t)(ebase + er * 8 + i) * DD + dc8] =
          make_float4(acc[i][0], acc[i][1], acc[i][2], acc[i][3]);
      *(float4*)&e_g[(size_t)(ebase + er * 8 + i) * DD + dc8 + 4] =
          make_float4(acc[i][4], acc[i][5], acc[i][6], acc[i][7]);
    }
    wr_panel(T, er, dc, acc);
    mv64<false>(T, W1b, b1v, er, dc, acc);          // m1 partial
    // elementwise 2: + Hc[row] + nb1, softplus
#pragma unroll
    for (int i = 0; i < 8; ++i) {
      const float4 hc0 = *(const float4*)&Hc[(size_t)r_[i] * DD + dc8];
      const float4 hc1 = *(const float4*)&Hc[(size_t)r_[i] * DD + dc8 + 4];
      const float gc[8] = {hc0.x, hc0.y, hc0.z, hc0.w, hc1.x, hc1.y, hc1.z, hc1.w};
#pragma unroll
      for (int j = 0; j < 8; ++j)
        acc[i][j] = sp_f(acc[i][j] + gc[j] + nb1v[j]);
    }
    wr_panel(T, er, dc, acc);
    mv64<true>(T, nW2, nb2v, er, dc, acc);          // msg
    // scatter-add messages to destination nodes
#pragma unroll
    for (int i = 0; i < 8; ++i)
#pragma unroll
      for (int j = 0; j < 8; ++j)
        atomicAdd(&hnew[(size_t)c_[i] * DD + dc8 + j], acc[i][j]);
  }
}

// per-channel sum & sumsq over h_new
__global__ __launch_bounds__(256)
void bn_stats_kernel(const float* __restrict__ hnew, float* __restrict__ stats) {
  int lane = threadIdx.x & 63, wid = threadIdx.x >> 6;
  int start = blockIdx.x * 4 + wid, step = gridDim.x * 4;
  float s = 0.f, q = 0.f;
  for (int n = start; n < N_ATOMS; n += step) {
    float v = hnew[(size_t)n * DD + lane];
    s += v;
    q = fmaf(v, v, q);
  }
  atomicAdd(&stats[lane], s);
  atomicAdd(&stats[DD + lane], q);
}

// h = sp(BN(h_new)) + h
__global__ __launch_bounds__(256)
void bn_apply_kernel(const float* __restrict__ hnew, const float* __restrict__ stats,
                     const float* __restrict__ gamma, const float* __restrict__ beta,
                     float* __restrict__ h) {
  int idx = blockIdx.x * 256 + threadIdx.x;   // N*64 = 3.2M exact
  int d = idx & 63;
  const float invN = 1.f / (float)N_ATOMS;
  float mu = stats[d] * invN;
  float var = fmaxf(stats[DD + d] * invN - mu * mu, 0.f);
  float inv = 1.f / sqrtf(var + 1e-5f);
  float hb = (hnew[idx] - mu) * inv * gamma[d] + beta[d];
  h[idx] = sp_f(hb) + h[idx];
}

__global__ __launch_bounds__(256)
void pool_kernel(const float* __restrict__ h, const int* __restrict__ batch,
                 float* __restrict__ gsum, float* __restrict__ cnt) {
  int n = blockIdx.x * 4 + (threadIdx.x >> 6);
  int lane = threadIdx.x & 63;
  if (n >= N_ATOMS) return;
  int b = batch[n];
  atomicAdd(&gsum[(size_t)b * DD + lane], h[(size_t)n * DD + lane]);
  if (lane == 0) atomicAdd(&cnt[b], 1.f);
}

__global__ __launch_bounds__(128)
void pred_kernel(const float* __restrict__ gsum, const float* __restrict__ cnt,
                 const float* __restrict__ W1, const float* __restrict__ b1,
                 const float* __restrict__ W2, const float* __restrict__ b2,
                 const float* __restrict__ W3, const float* __restrict__ b3,
                 float* __restrict__ out) {
  __shared__ float sg[DD];
  __shared__ float so[HH];
  int g = blockIdx.x, t = threadIdx.x;
  if (t < DD) sg[t] = gsum[(size_t)g * DD + t] / fmaxf(cnt[g], 1.f);
  __syncthreads();
  float a = b1[t];
#pragma unroll
  for (int k = 0; k < DD; ++k) a = fmaf(sg[k], W1[k * HH + t], a);
  a = sp_f(a);
  so[t] = a;
  __syncthreads();
  float o = b2[t];
#pragma unroll
  for (int k = 0; k < HH; ++k) o = fmaf(so[k], W2[k * HH + t], o);
  o = sp_f(o);
  float contrib = o * W3[t];
  __syncthreads();
  so[t] = contrib;
  __syncthreads();
  if (t < 64) so[t] += so[t + 64];
  __syncthreads();
  if (t == 0) {
    float s = 0.f;
    for (int k = 0; k < 64; ++k) s += so[k];
    out[g] = s + b3[0];
  }
}

extern "C" void kernel_launch(void* const* d_in, const int* in_sizes, int n_in,
                              void* d_out, int out_size, void* d_ws, size_t ws_size,
                              hipStream_t stream) {
  const float* x         = (const float*)d_in[0];
  const float* edge_attr = (const float*)d_in[1];
  const int*   eidx      = (const int*)d_in[2];
  const int*   batch     = (const int*)d_in[3];
  const float* atom_W    = (const float*)d_in[4];
  const float* atom_b    = (const float*)d_in[5];
  const float* bond_W    = (const float*)d_in[6];
  const float* bond_b    = (const float*)d_in[7];
  const float* nu_W1     = (const float*)d_in[8];
  const float* nu_b1     = (const float*)d_in[9];
  const float* nu_W2     = (const float*)d_in[10];
  const float* nu_b2     = (const float*)d_in[11];
  const float* eu_W1     = (const float*)d_in[12];
  const float* eu_b1     = (const float*)d_in[13];
  const float* eu_W2     = (const float*)d_in[14];
  const float* eu_b2     = (const float*)d_in[15];
  const float* bn_gamma  = (const float*)d_in[16];
  const float* bn_beta   = (const float*)d_in[17];
  const float* pW1       = (const float*)d_in[18];
  const float* pb1       = (const float*)d_in[19];
  const float* pW2       = (const float*)d_in[20];
  const float* pb2       = (const float*)d_in[21];
  const float* pW3       = (const float*)d_in[22];
  const float* pb3       = (const float*)d_in[23];
  float* out = (float*)d_out;

  // workspace layout (floats)
  float* ws   = (float*)d_ws;
  float* h    = ws;                  // 3.2M
  float* hnew = ws + 3200000;        // 3.2M
  float* Ha   = ws + 6400000;        // 3.2M
  float* Hb   = ws + 9600000;        // 3.2M
  float* Hc   = ws + 12800000;       // 3.2M
  float* stats= ws + 16000000;       // 128
  float* gsum = ws + 16000128;       // 65536
  float* cnt  = ws + 16065664;       // 1024
  float* e    = ws + 16115840;       // 76.8M

  const int* row = eidx;
  const int* col = eidx + N_EDGES;

  atom_embed_kernel<<<N_ATOMS / 4, 256, 0, stream>>>(x, atom_W, atom_b, h);
  bond_embed_kernel<<<N_EDGES / 4, 256, 0, stream>>>(edge_attr, bond_W, bond_b, e);

  for (int i = 0; i < LL; ++i) {
    // weight sub-blocks straight from inputs (k-major already)
    const float* Wa  = eu_W1 + (size_t)i * 192 * DD;           // h[row] part of eu_W1
    const float* Wb  = Wa + 64 * DD;                           // h[col] part
    const float* W1c = Wa + 128 * DD;                          // e part
    const float* W2  = eu_W2 + (size_t)i * DD * DD;
    const float* Wc  = nu_W1 + (size_t)i * 128 * DD;           // h[row] part of nu_W1
    const float* W1b = Wc + 64 * DD;                           // e part
    const float* nW2 = nu_W2 + (size_t)i * DD * DD;
    node_pre_kernel<<<N_ATOMS / 4, 256, 0, stream>>>(h, Wa, Wb, Wc, Ha, Hb, Hc);
    hipMemsetAsync(hnew, 0, (size_t)N_ATOMS * DD * sizeof(float), stream);
    hipMemsetAsync(stats, 0, 128 * sizeof(float), stream);
    edge_layer_kernel<<<512, 256, 0, stream>>>(
        Ha, Hb, Hc, e, row, col,
        W1c, W2, W1b, nW2,
        eu_b1 + i * DD, eu_b2 + i * DD, nu_b1 + i * DD, nu_b2 + i * DD,
        hnew, NBATCH);
    bn_stats_kernel<<<128, 256, 0, stream>>>(hnew, stats);
    bn_apply_kernel<<<N_ATOMS * DD / 256, 256, 0, stream>>>(
        hnew, stats, bn_gamma + i * DD, bn_beta + i * DD, h);
  }

  hipMemsetAsync(gsum, 0, (65536 + 1024) * sizeof(float), stream);
  pool_kernel<<<N_ATOMS / 4, 256, 0, stream>>>(h, batch, gsum, cnt);
  pred_kernel<<<GG, 128, 0, stream>>>(gsum, cnt, pW1, pb1, pW2, pb2, pW3, pb3, out);
}

// Round 3
// 5585.019 us; speedup vs baseline: 1.5411x; 1.5411x over previous
//
#include <hip/hip_runtime.h>
#include <hip/hip_bf16.h>

// CGCNN-PyG forward. Sizes fixed per reference.
#define N_ATOMS 50000
#define N_EDGES 1200000
#define FA 92
#define FB 41
#define DD 64
#define HH 128
#define LL 3
#define GG 1024
#define NBATCH (N_EDGES / 64)   // 18750, exact
#define PADW 65                 // 64+1 pad: conflict-free rows AND columns

// stable softplus matching jax.nn.softplus = max(x,0) + log1p(exp(-|x|))
__device__ __forceinline__ float sp_f(float x) {
  float ax = fabsf(x);
  float e  = __expf(-ax);
  float l  = __logf(1.f + e);
  return fmaxf(x, 0.f) + l;
}

// 64x64 matvec, lane=edge: u[] per-edge vector in regs, WT d-major [d][k]
// (uniform address stream -> s_load; SGPR operand to v_fmac). Result rows
// written to panel T[d][lane] (stride PADW, conflict-free).
template<bool HASBIAS>
__device__ __forceinline__ void mv64(const float (&u)[DD], const float* __restrict__ WT,
                                     const float* __restrict__ bias,
                                     float* __restrict__ T, int lane) {
  for (int dt = 0; dt < DD; dt += 8) {   // runtime loop keeps I$ small
    float acc[8];
#pragma unroll
    for (int t = 0; t < 8; ++t) acc[t] = HASBIAS ? bias[dt + t] : 0.f;
#pragma unroll
    for (int k = 0; k < DD; ++k) {
#pragma unroll
      for (int t = 0; t < 8; ++t) acc[t] = fmaf(u[k], WT[(dt + t) * DD + k], acc[t]);
    }
#pragma unroll
    for (int t = 0; t < 8; ++t) T[(dt + t) * PADW + lane] = acc[t];
  }
}

// h = x @ atom_W + atom_b   [N,92]->[N,64]; 16 rows per 64-thr block (uniform n)
__global__ __launch_bounds__(64)
void atom_embed_kernel(const float* __restrict__ x, const float* __restrict__ W,
                       const float* __restrict__ b, float* __restrict__ h) {
  int lane = threadIdx.x;
  float bl = b[lane];
  for (int i = 0; i < 16; ++i) {
    int n = blockIdx.x * 16 + i;          // uniform
    float acc = bl;
    const float* xr = x + (size_t)n * FA; // uniform row -> s_load
#pragma unroll
    for (int k = 0; k < FA; ++k) acc = fmaf(xr[k], W[k * DD + lane], acc);
    h[(size_t)n * DD + lane] = acc;
  }
}

// e = edge_attr @ bond_W + bond_b   [E,41]->[E,64]; 16 rows per block
__global__ __launch_bounds__(64)
void bond_embed_kernel(const float* __restrict__ ea, const float* __restrict__ W,
                       const float* __restrict__ b, float* __restrict__ e) {
  int lane = threadIdx.x;
  float bl = b[lane];
  for (int i = 0; i < 16; ++i) {
    int eg = blockIdx.x * 16 + i;         // uniform
    float acc = bl;
    const float* er = ea + (size_t)eg * FB;
#pragma unroll
    for (int k = 0; k < FB; ++k) acc = fmaf(er[k], W[k * DD + lane], acc);
    e[(size_t)eg * DD + lane] = acc;
  }
}

// Ha = h@Wa, Hb = h@Wb, Hc = h@Wc; also zeroes hnew rows (+ block0 zeroes stats)
__global__ __launch_bounds__(64)
void node_pre_kernel(const float* __restrict__ h, const float* __restrict__ Wa,
                     const float* __restrict__ Wb, const float* __restrict__ Wc,
                     float* __restrict__ Ha, float* __restrict__ Hb, float* __restrict__ Hc,
                     float* __restrict__ hnew, float* __restrict__ stats) {
  int lane = threadIdx.x;
  if (blockIdx.x == 0) { stats[lane] = 0.f; stats[DD + lane] = 0.f; }
  for (int i = 0; i < 16; ++i) {
    int n = blockIdx.x * 16 + i;          // uniform
    float a = 0.f, bb = 0.f, c = 0.f;
    const float* hr = h + (size_t)n * DD; // uniform row -> s_load
#pragma unroll
    for (int k = 0; k < DD; ++k) {
      float hv = hr[k];
      a  = fmaf(hv, Wa[k * DD + lane], a);
      bb = fmaf(hv, Wb[k * DD + lane], bb);
      c  = fmaf(hv, Wc[k * DD + lane], c);
    }
    Ha[(size_t)n * DD + lane] = a;
    Hb[(size_t)n * DD + lane] = bb;
    Hc[(size_t)n * DD + lane] = c;
    hnew[(size_t)n * DD + lane] = 0.f;
  }
}

// transpose the 4 per-edge 64x64 matrices of every layer to d-major [d][k]
__global__ void prep_wt_kernel(const float* __restrict__ eu_W1, const float* __restrict__ eu_W2,
                               const float* __restrict__ nu_W1, const float* __restrict__ nu_W2,
                               float* __restrict__ wt) {
  int tid = blockIdx.x * 256 + threadIdx.x;
  if (tid >= LL * 4 * DD * DD) return;
  int mat = tid >> 12;          // /4096
  int idx = tid & 4095;
  int layer = mat >> 2, m = mat & 3;
  int d = idx >> 6, k = idx & 63;
  float v;
  if      (m == 0) v = eu_W1[layer * 192 * DD + (128 + k) * DD + d];  // W1c (e part of eu_W1)
  else if (m == 1) v = eu_W2[layer * DD * DD + k * DD + d];           // W2
  else if (m == 2) v = nu_W1[layer * 128 * DD + (64 + k) * DD + d];   // W1b (e part of nu_W1)
  else             v = nu_W2[layer * DD * DD + k * DD + d];           // nW2
  wt[layer * 4 * DD * DD + m * DD * DD + d * DD + k] = v;
}

// Fused per-edge layer. One 64-edge batch per single-wave block (blockIdx = batch):
//   stage e^T -> mv(W1c) -> [+Ha[r]+Hb[c]+b1, sp] -> mv(W2)+b2 = e_new (in place)
//   -> mv(W1b) -> [+Hc[r]+nb1, sp] -> mv(nW2)+nb2 = msg -> atomic scatter.
// All control flow + weight/index addresses are wave-uniform -> s_load path.
__global__ __launch_bounds__(64, 2)
void edge_layer_kernel(const float* __restrict__ Ha, const float* __restrict__ Hb,
                       const float* __restrict__ Hc, float* __restrict__ e_g,
                       const int* __restrict__ row_g, const int* __restrict__ col_g,
                       const float* __restrict__ W1cT, const float* __restrict__ W2T,
                       const float* __restrict__ W1bT, const float* __restrict__ nW2T,
                       const float* __restrict__ b1, const float* __restrict__ b2,
                       const float* __restrict__ nb1, const float* __restrict__ nb2,
                       float* __restrict__ hnew) {
  __shared__ float T[DD * PADW];          // 16,640 B -> 9 blocks/CU
  const int lane = threadIdx.x;
  const int ebase = blockIdx.x * 64;      // uniform
  const float b1l = b1[lane];
  const float nb1l = nb1[lane];
  float u[DD];

  // stage e^T into panel (lane = channel, coalesced reads, column writes)
#pragma unroll 8
  for (int el = 0; el < 64; ++el)
    T[lane * PADW + el] = e_g[(size_t)(ebase + el) * DD + lane];
  __syncthreads();
#pragma unroll
  for (int k = 0; k < DD; ++k) u[k] = T[k * PADW + lane];   // lane = edge
  __syncthreads();
  mv64<false>(u, W1cT, nullptr, T, lane);                   // t1 partial -> T
  __syncthreads();

  // elementwise 1: += Ha[row] + Hb[col] + b1, softplus (lane = channel)
  for (int c0 = 0; c0 < 64; c0 += 16) {
    int r16[16], c16[16];
#pragma unroll
    for (int t = 0; t < 16; ++t) {        // uniform index loads -> s_load
      r16[t] = row_g[ebase + c0 + t];
      c16[t] = col_g[ebase + c0 + t];
    }
#pragma unroll
    for (int t = 0; t < 16; ++t) {
      float v = T[lane * PADW + c0 + t]
              + Ha[(size_t)r16[t] * DD + lane]
              + Hb[(size_t)c16[t] * DD + lane] + b1l;
      T[lane * PADW + c0 + t] = sp_f(v);
    }
  }
  __syncthreads();
#pragma unroll
  for (int k = 0; k < DD; ++k) u[k] = T[k * PADW + lane];
  __syncthreads();
  mv64<true>(u, W2T, b2, T, lane);                          // e_new -> T
  __syncthreads();

  // write updated e (in place, lane = channel, coalesced)
#pragma unroll 8
  for (int el = 0; el < 64; ++el)
    e_g[(size_t)(ebase + el) * DD + lane] = T[lane * PADW + el];
#pragma unroll
  for (int k = 0; k < DD; ++k) u[k] = T[k * PADW + lane];
  __syncthreads();
  mv64<false>(u, W1bT, nullptr, T, lane);                   // m1 partial -> T
  __syncthreads();

  // elementwise 2: += Hc[row] + nb1, softplus
  for (int c0 = 0; c0 < 64; c0 += 16) {
    int r16[16];
#pragma unroll
    for (int t = 0; t < 16; ++t) r16[t] = row_g[ebase + c0 + t];
#pragma unroll
    for (int t = 0; t < 16; ++t) {
      float v = T[lane * PADW + c0 + t] + Hc[(size_t)r16[t] * DD + lane] + nb1l;
      T[lane * PADW + c0 + t] = sp_f(v);
    }
  }
  __syncthreads();
#pragma unroll
  for (int k = 0; k < DD; ++k) u[k] = T[k * PADW + lane];
  __syncthreads();
  mv64<true>(u, nW2T, nb2, T, lane);                        // msg -> T
  __syncthreads();

  // scatter-add messages to destination nodes (lane = channel, coalesced)
  for (int c0 = 0; c0 < 64; c0 += 16) {
    int c16[16];
#pragma unroll
    for (int t = 0; t < 16; ++t) c16[t] = col_g[ebase + c0 + t];
#pragma unroll
    for (int t = 0; t < 16; ++t)
      atomicAdd(&hnew[(size_t)c16[t] * DD + lane], T[lane * PADW + c0 + t]);
  }
}

// per-channel sum & sumsq over h_new; optionally zero gsum/cnt (last layer)
__global__ __launch_bounds__(256)
void bn_stats_kernel(const float* __restrict__ hnew, float* __restrict__ stats,
                     float* __restrict__ gz) {
  int tid = blockIdx.x * 256 + threadIdx.x;
  if (gz) {
    for (int i = tid; i < GG * DD + GG; i += 128 * 256) gz[i] = 0.f;
  }
  int lane = threadIdx.x & 63, wid = threadIdx.x >> 6;
  int start = blockIdx.x * 4 + wid, step = gridDim.x * 4;
  float s = 0.f, q = 0.f;
  for (int n = start; n < N_ATOMS; n += step) {
    float v = hnew[(size_t)n * DD + lane];
    s += v;
    q = fmaf(v, v, q);
  }
  atomicAdd(&stats[lane], s);
  atomicAdd(&stats[DD + lane], q);
}

// h = sp(BN(h_new)) + h ; on last layer also pool into gsum/cnt
__global__ __launch_bounds__(256)
void bn_apply_kernel(const float* __restrict__ hnew, const float* __restrict__ stats,
                     const float* __restrict__ gamma, const float* __restrict__ beta,
                     float* __restrict__ h, const int* __restrict__ batch,
                     float* __restrict__ gsum, float* __restrict__ cnt) {
  int idx = blockIdx.x * 256 + threadIdx.x;   // N*64 = 3.2M exact
  int d = idx & 63;
  const float invN = 1.f / (float)N_ATOMS;
  float mu = stats[d] * invN;
  float var = fmaxf(stats[DD + d] * invN - mu * mu, 0.f);
  float inv = 1.f / sqrtf(var + 1e-5f);
  float hb = (hnew[idx] - mu) * inv * gamma[d] + beta[d];
  float hv = sp_f(hb) + h[idx];
  h[idx] = hv;
  if (batch) {
    int n = idx >> 6;
    int b = batch[n];
    atomicAdd(&gsum[(size_t)b * DD + d], hv);
    if (d == 0) atomicAdd(&cnt[b], 1.f);
  }
}

__global__ __launch_bounds__(128)
void pred_kernel(const float* __restrict__ gsum, const float* __restrict__ cnt,
                 const float* __restrict__ W1, const float* __restrict__ b1,
                 const float* __restrict__ W2, const float* __restrict__ b2,
                 const float* __restrict__ W3, const float* __restrict__ b3,
                 float* __restrict__ out) {
  __shared__ float sg[DD];
  __shared__ float so[HH];
  int g = blockIdx.x, t = threadIdx.x;
  if (t < DD) sg[t] = gsum[(size_t)g * DD + t] / fmaxf(cnt[g], 1.f);
  __syncthreads();
  float a = b1[t];
#pragma unroll
  for (int k = 0; k < DD; ++k) a = fmaf(sg[k], W1[k * HH + t], a);
  a = sp_f(a);
  so[t] = a;
  __syncthreads();
  float o = b2[t];
#pragma unroll
  for (int k = 0; k < HH; ++k) o = fmaf(so[k], W2[k * HH + t], o);
  o = sp_f(o);
  float contrib = o * W3[t];
  __syncthreads();
  so[t] = contrib;
  __syncthreads();
  if (t < 64) so[t] += so[t + 64];
  __syncthreads();
  if (t == 0) {
    float s = 0.f;
    for (int k = 0; k < 64; ++k) s += so[k];
    out[g] = s + b3[0];
  }
}

extern "C" void kernel_launch(void* const* d_in, const int* in_sizes, int n_in,
                              void* d_out, int out_size, void* d_ws, size_t ws_size,
                              hipStream_t stream) {
  const float* x         = (const float*)d_in[0];
  const float* edge_attr = (const float*)d_in[1];
  const int*   eidx      = (const int*)d_in[2];
  const int*   batch     = (const int*)d_in[3];
  const float* atom_W    = (const float*)d_in[4];
  const float* atom_b    = (const float*)d_in[5];
  const float* bond_W    = (const float*)d_in[6];
  const float* bond_b    = (const float*)d_in[7];
  const float* nu_W1     = (const float*)d_in[8];
  const float* nu_b1     = (const float*)d_in[9];
  const float* nu_W2     = (const float*)d_in[10];
  const float* nu_b2     = (const float*)d_in[11];
  const float* eu_W1     = (const float*)d_in[12];
  const float* eu_b1     = (const float*)d_in[13];
  const float* eu_W2     = (const float*)d_in[14];
  const float* eu_b2     = (const float*)d_in[15];
  const float* bn_gamma  = (const float*)d_in[16];
  const float* bn_beta   = (const float*)d_in[17];
  const float* pW1       = (const float*)d_in[18];
  const float* pb1       = (const float*)d_in[19];
  const float* pW2       = (const float*)d_in[20];
  const float* pb2       = (const float*)d_in[21];
  const float* pW3       = (const float*)d_in[22];
  const float* pb3       = (const float*)d_in[23];
  float* out = (float*)d_out;

  // workspace layout (floats)
  float* ws   = (float*)d_ws;
  float* h    = ws;                  // 3.2M
  float* hnew = ws + 3200000;        // 3.2M
  float* Ha   = ws + 6400000;        // 3.2M
  float* Hb   = ws + 9600000;        // 3.2M
  float* Hc   = ws + 12800000;       // 3.2M
  float* stats= ws + 16000000;       // 128
  float* gsum = ws + 16000128;       // 65536
  float* cnt  = ws + 16065664;       // 1024  (contiguous after gsum)
  float* wt   = ws + 16066688;       // 49152
  float* e    = ws + 16115840;       // 76.8M

  const int* row = eidx;
  const int* col = eidx + N_EDGES;

  prep_wt_kernel<<<192, 256, 0, stream>>>(eu_W1, eu_W2, nu_W1, nu_W2, wt);
  atom_embed_kernel<<<N_ATOMS / 16, 64, 0, stream>>>(x, atom_W, atom_b, h);
  bond_embed_kernel<<<N_EDGES / 16, 64, 0, stream>>>(edge_attr, bond_W, bond_b, e);

  for (int i = 0; i < LL; ++i) {
    const float* Wa  = eu_W1 + (size_t)i * 192 * DD;           // h[row] part of eu_W1
    const float* Wb  = Wa + 64 * DD;                           // h[col] part
    const float* Wc  = nu_W1 + (size_t)i * 128 * DD;           // h[row] part of nu_W1
    node_pre_kernel<<<N_ATOMS / 16, 64, 0, stream>>>(h, Wa, Wb, Wc, Ha, Hb, Hc,
                                                     hnew, stats);
    const float* wl = wt + (size_t)i * 4 * DD * DD;
    edge_layer_kernel<<<NBATCH, 64, 0, stream>>>(
        Ha, Hb, Hc, e, row, col,
        wl, wl + DD * DD, wl + 2 * DD * DD, wl + 3 * DD * DD,
        eu_b1 + i * DD, eu_b2 + i * DD, nu_b1 + i * DD, nu_b2 + i * DD,
        hnew);
    bn_stats_kernel<<<128, 256, 0, stream>>>(hnew, stats,
                                             (i == LL - 1) ? gsum : (float*)nullptr);
    bn_apply_kernel<<<N_ATOMS * DD / 256, 256, 0, stream>>>(
        hnew, stats, bn_gamma + i * DD, bn_beta + i * DD, h,
        (i == LL - 1) ? batch : (const int*)nullptr, gsum, cnt);
  }

  pred_kernel<<<GG, 128, 0, stream>>>(gsum, cnt, pW1, pb1, pW2, pb2, pW3, pb3, out);
}

// Round 4
// 3638.308 us; speedup vs baseline: 2.3657x; 1.5351x over previous
//
#include <hip/hip_runtime.h>
#include <hip/hip_bf16.h>

// CGCNN-PyG forward, MFMA bf16-split edition. Sizes fixed per reference.
#define N_ATOMS 50000
#define N_EDGES 1200000
#define FA 92
#define FB 41
#define DD 64
#define HH 128
#define LL 3
#define GG 1024
#define NBATCH (N_EDGES / 64)        // 18750 exact
#define NGROUP ((N_ATOMS + 63) / 64) // 782
#define PST 68                       // panel stride (words): even bank spread for frag reads

typedef __attribute__((ext_vector_type(8))) short s16x8;  // 8 bf16 (4 VGPR) MFMA A/B frag
typedef __attribute__((ext_vector_type(4))) float f32x4;  // MFMA C/D frag

// stable softplus matching jax.nn.softplus
__device__ __forceinline__ float sp_f(float x) {
  float ax = fabsf(x);
  float e  = __expf(-ax);
  float l  = __logf(1.f + e);
  return fmaxf(x, 0.f) + l;
}

// split 8 f32 (two f32x4) into hi/lo bf16 fragments (truncation split: exact residual)
__device__ __forceinline__ void split8(f32x4 q0, f32x4 q1, s16x8& hi, s16x8& lo) {
#pragma unroll
  for (int j = 0; j < 4; ++j) {
    unsigned u0 = __float_as_uint(q0[j]) & 0xffff0000u;
    unsigned u1 = __float_as_uint(q1[j]) & 0xffff0000u;
    float r0 = q0[j] - __uint_as_float(u0);
    float r1 = q1[j] - __uint_as_float(u1);
    hi[j]     = (short)(u0 >> 16);
    hi[4 + j] = (short)(u1 >> 16);
    lo[j]     = (short)(__float_as_uint(r0) >> 16);
    lo[4 + j] = (short)(__float_as_uint(r1) >> 16);
  }
}

// 3-term split product accumulate: C += Ah*Bh + Ah*Bl + Al*Bh
__device__ __forceinline__ f32x4 mm3(s16x8 ah, s16x8 al, s16x8 bh, s16x8 bl, f32x4 c) {
  c = __builtin_amdgcn_mfma_f32_16x16x32_bf16(ah, bh, c, 0, 0, 0);
  c = __builtin_amdgcn_mfma_f32_16x16x32_bf16(ah, bl, c, 0, 0, 0);
  c = __builtin_amdgcn_mfma_f32_16x16x32_bf16(al, bh, c, 0, 0, 0);
  return c;
}

// Pack 21 64x64 matrices into MFMA B-fragment order, hi/lo bf16.
// mats 0..11: per layer {W1c, W2, W1b, nW2}; mats 12..20: per layer {Wa, Wb, Wc}.
// Per mat: 16KB = 16 tiles (8 hi then 8 lo) x 64 lanes x 8 bf16.
// k-map per lane: k = kt*32 + (j>>2)*16 + (lane>>4)*4 + (j&3)  (same map used by all A reads)
__global__ __launch_bounds__(256)
void prep_pack_kernel(const float* __restrict__ eu_W1, const float* __restrict__ eu_W2,
                      const float* __restrict__ nu_W1, const float* __restrict__ nu_W2,
                      short* __restrict__ wp) {
  int tid = blockIdx.x * 256 + threadIdx.x;
  if (tid >= 21 * 512) return;
  int mat = tid >> 9, rem = tid & 511;
  int tile = rem >> 6, lane = rem & 63;
  int kt = tile >> 2, n0 = tile & 3;
  int n = n0 * 16 + (lane & 15);
  int layer, kind;
  if (mat < 12) { layer = mat >> 2; kind = mat & 3; }
  else { int t = mat - 12; layer = t / 3; kind = 4 + t % 3; }
  const float* base; int koff;
  switch (kind) {
    case 0: base = eu_W1 + (size_t)layer * 192 * DD; koff = 128; break; // W1c (e part)
    case 1: base = eu_W2 + (size_t)layer * DD * DD;  koff = 0;   break; // W2
    case 2: base = nu_W1 + (size_t)layer * 128 * DD; koff = 64;  break; // W1b (e part)
    case 3: base = nu_W2 + (size_t)layer * DD * DD;  koff = 0;   break; // nW2
    case 4: base = eu_W1 + (size_t)layer * 192 * DD; koff = 0;   break; // Wa (h[row])
    case 5: base = eu_W1 + (size_t)layer * 192 * DD; koff = 64;  break; // Wb (h[col])
    default: base = nu_W1 + (size_t)layer * 128 * DD; koff = 0;  break; // Wc (h[row])
  }
  short* dhi = wp + (size_t)mat * 8192 + (size_t)(tile * 64 + lane) * 8;
  short* dlo = dhi + 4096;
#pragma unroll
  for (int j = 0; j < 8; ++j) {
    int k = kt * 32 + (j >> 2) * 16 + ((lane >> 4) << 2) + (j & 3);
    float w = base[(size_t)(koff + k) * DD + n];
    unsigned hb = __float_as_uint(w) & 0xffff0000u;
    float r = w - __uint_as_float(hb);
    dhi[j] = (short)(hb >> 16);
    dlo[j] = (short)(__float_as_uint(r) >> 16);
  }
}

// h = x @ atom_W + atom_b : weights-in-VGPR (92/lane), x rows broadcast from LDS
__global__ __launch_bounds__(64)
void atom_embed_kernel(const float* __restrict__ x, const float* __restrict__ W,
                       const float* __restrict__ b, float* __restrict__ h) {
  __shared__ float xs[16 * FA];
  int lane = threadIdx.x;
  float w[FA];
#pragma unroll
  for (int k = 0; k < FA; ++k) w[k] = W[k * DD + lane];
  float bl = b[lane];
  int rbase = blockIdx.x * 16;
  for (int i = lane; i < 16 * FA; i += 64) xs[i] = x[(size_t)rbase * FA + i];
  __syncthreads();
  for (int r = 0; r < 16; ++r) {
    float acc = bl;
#pragma unroll
    for (int k = 0; k < FA; ++k) acc = fmaf(xs[r * FA + k], w[k], acc);
    h[(size_t)(rbase + r) * DD + lane] = acc;
  }
}

// e = edge_attr @ bond_W + bond_b : same pattern (41 weights/lane)
__global__ __launch_bounds__(64)
void bond_embed_kernel(const float* __restrict__ ea, const float* __restrict__ W,
                       const float* __restrict__ b, float* __restrict__ e) {
  __shared__ float xs[16 * FB];
  int lane = threadIdx.x;
  float w[FB];
#pragma unroll
  for (int k = 0; k < FB; ++k) w[k] = W[k * DD + lane];
  float bl = b[lane];
  int rbase = blockIdx.x * 16;
  for (int i = lane; i < 16 * FB; i += 64) xs[i] = ea[(size_t)rbase * FB + i];
  __syncthreads();
  for (int r = 0; r < 16; ++r) {
    float acc = bl;
#pragma unroll
    for (int k = 0; k < FB; ++k) acc = fmaf(xs[r * FB + k], w[k], acc);
    e[(size_t)(rbase + r) * DD + lane] = acc;
  }
}

// Ha=h@Wa, Hb=h@Wb, Hc=h@Wc via MFMA split; also zeroes hnew rows + stats
__global__ __launch_bounds__(256, 2)
void node_pre_kernel(const float* __restrict__ h, const short* __restrict__ wp, int layer,
                     float* __restrict__ Ha, float* __restrict__ Hb, float* __restrict__ Hc,
                     float* __restrict__ hnew, float* __restrict__ stats) {
  const int wid = threadIdx.x >> 6;
  const int lane = threadIdx.x & 63;
  const int lr = lane & 15, lh = lane >> 4;
  if (blockIdx.x == 0 && wid == 0) { stats[lane] = 0.f; stats[DD + lane] = 0.f; }
  const int g = blockIdx.x * 4 + wid;
  if (g >= NGROUP) return;
  const int gbase = g * 64;
#pragma unroll
  for (int m = 0; m < 16; ++m) {
    int r = gbase + m * 4 + lh;
    if (r < N_ATOMS) *(f32x4*)&hnew[(size_t)r * DD + lr * 4] = (f32x4){0.f, 0.f, 0.f, 0.f};
  }
  s16x8 Ah[4][2], Al[4][2];
#pragma unroll
  for (int m0 = 0; m0 < 4; ++m0) {
    int r = gbase + m0 * 16 + lr;
    bool ok = r < N_ATOMS;
    const float* hr = h + (size_t)(ok ? r : 0) * DD;
#pragma unroll
    for (int kt = 0; kt < 2; ++kt) {
      f32x4 q0 = ok ? *(const f32x4*)(hr + kt * 32 + lh * 4) : (f32x4){0.f, 0.f, 0.f, 0.f};
      f32x4 q1 = ok ? *(const f32x4*)(hr + kt * 32 + 16 + lh * 4) : (f32x4){0.f, 0.f, 0.f, 0.f};
      split8(q0, q1, Ah[m0][kt], Al[m0][kt]);
    }
  }
#pragma unroll
  for (int mat = 0; mat < 3; ++mat) {
    const s16x8* Wm = (const s16x8*)wp + (size_t)(12 + layer * 3 + mat) * 1024;
    s16x8 Bh[2][4], Bl[2][4];
#pragma unroll
    for (int kt = 0; kt < 2; ++kt)
#pragma unroll
      for (int n0 = 0; n0 < 4; ++n0) {
        Bh[kt][n0] = Wm[(kt * 4 + n0) * 64 + lane];
        Bl[kt][n0] = Wm[512 + (kt * 4 + n0) * 64 + lane];
      }
    f32x4 C[4][4];
#pragma unroll
    for (int m0 = 0; m0 < 4; ++m0) {
#pragma unroll
      for (int n0 = 0; n0 < 4; ++n0) C[m0][n0] = (f32x4){0.f, 0.f, 0.f, 0.f};
#pragma unroll
      for (int kt = 0; kt < 2; ++kt)
#pragma unroll
        for (int n0 = 0; n0 < 4; ++n0)
          C[m0][n0] = mm3(Ah[m0][kt], Al[m0][kt], Bh[kt][n0], Bl[kt][n0], C[m0][n0]);
    }
    float* o = (mat == 0) ? Ha : (mat == 1) ? Hb : Hc;
#pragma unroll
    for (int m0 = 0; m0 < 4; ++m0)
#pragma unroll
      for (int i = 0; i < 4; ++i) {
        int r = gbase + m0 * 16 + lh * 4 + i;
        if (r < N_ATOMS) {
#pragma unroll
          for (int n0 = 0; n0 < 4; ++n0)
            o[(size_t)r * DD + n0 * 16 + lr] = C[m0][n0][i];
        }
      }
  }
}

// Fused per-edge layer, MFMA split. Per 64-edge batch (one wave):
// C1 = e@W1c -> sp(C1+Ha[r]+Hb[c]+b1) -> panel -> C2 = @W2+b2 = e_new (global+panel)
// -> C3 = @W1b -> sp(C3+Hc[r]+nb1) -> panel -> C4 = @nW2+nb2 = msg -> atomic scatter
__global__ __launch_bounds__(256, 2)
void edge_layer_kernel(const float* __restrict__ Ha, const float* __restrict__ Hb,
                       const float* __restrict__ Hc, float* __restrict__ e_g,
                       const int* __restrict__ row_g, const int* __restrict__ col_g,
                       const short* __restrict__ wp, int layer,
                       const float* __restrict__ b1, const float* __restrict__ b2,
                       const float* __restrict__ nb1, const float* __restrict__ nb2,
                       float* __restrict__ hnew) {
  __shared__ __align__(16) float T4[4][DD * PST];  // 69,632 B -> 2 blocks/CU
  const int wid = threadIdx.x >> 6;
  const int lane = threadIdx.x & 63;
  const int lr = lane & 15, lh = lane >> 4;
  float* T = T4[wid];
  float b1f[4], b2f[4], nb1f[4], nb2f[4];
#pragma unroll
  for (int n0 = 0; n0 < 4; ++n0) {
    b1f[n0]  = b1[n0 * 16 + lr];
    b2f[n0]  = b2[n0 * 16 + lr];
    nb1f[n0] = nb1[n0 * 16 + lr];
    nb2f[n0] = nb2[n0 * 16 + lr];
  }
  const s16x8* Wmat = (const s16x8*)wp + (size_t)layer * 4096;  // 4 mats x 1024 frags

  for (int b = blockIdx.x * 4 + wid; b < NBATCH; b += 2048) {
    const int ebase = b * 64;
    f32x4 C[4][4];
    s16x8 Bh[2][4], Bl[2][4];

    // ---------- stage 1: C = e @ W1c (A direct from global) ----------
#pragma unroll
    for (int kt = 0; kt < 2; ++kt)
#pragma unroll
      for (int n0 = 0; n0 < 4; ++n0) {
        Bh[kt][n0] = Wmat[(kt * 4 + n0) * 64 + lane];
        Bl[kt][n0] = Wmat[512 + (kt * 4 + n0) * 64 + lane];
      }
#pragma unroll
    for (int m0 = 0; m0 < 4; ++m0) {
#pragma unroll
      for (int n0 = 0; n0 < 4; ++n0) C[m0][n0] = (f32x4){0.f, 0.f, 0.f, 0.f};
      const float* ar = e_g + (size_t)(ebase + m0 * 16 + lr) * DD;
#pragma unroll
      for (int kt = 0; kt < 2; ++kt) {
        f32x4 q0 = *(const f32x4*)(ar + kt * 32 + lh * 4);
        f32x4 q1 = *(const f32x4*)(ar + kt * 32 + 16 + lh * 4);
        s16x8 ah, al;
        split8(q0, q1, ah, al);
#pragma unroll
        for (int n0 = 0; n0 < 4; ++n0)
          C[m0][n0] = mm3(ah, al, Bh[kt][n0], Bl[kt][n0], C[m0][n0]);
      }
    }
    // ---------- elementwise 1 -> panel ----------
#pragma unroll
    for (int m0 = 0; m0 < 4; ++m0)
#pragma unroll
      for (int i = 0; i < 4; ++i) {
        int r = row_g[ebase + m0 * 16 + lh * 4 + i];
        int c = col_g[ebase + m0 * 16 + lh * 4 + i];
        const float* har = Ha + (size_t)r * DD;
        const float* hbr = Hb + (size_t)c * DD;
#pragma unroll
        for (int n0 = 0; n0 < 4; ++n0) {
          float v = C[m0][n0][i] + har[n0 * 16 + lr] + hbr[n0 * 16 + lr] + b1f[n0];
          T[(m0 * 16 + lh * 4 + i) * PST + n0 * 16 + lr] = sp_f(v);
        }
      }
    // ---------- stage 2: C = panel @ W2 + b2 ----------
#pragma unroll
    for (int kt = 0; kt < 2; ++kt)
#pragma unroll
      for (int n0 = 0; n0 < 4; ++n0) {
        Bh[kt][n0] = Wmat[1024 + (kt * 4 + n0) * 64 + lane];
        Bl[kt][n0] = Wmat[1024 + 512 + (kt * 4 + n0) * 64 + lane];
      }
#pragma unroll
    for (int m0 = 0; m0 < 4; ++m0) {
#pragma unroll
      for (int n0 = 0; n0 < 4; ++n0) C[m0][n0] = (f32x4){b2f[n0], b2f[n0], b2f[n0], b2f[n0]};
      const float* pr = T + (m0 * 16 + lr) * PST;
#pragma unroll
      for (int kt = 0; kt < 2; ++kt) {
        f32x4 q0 = *(const f32x4*)(pr + kt * 32 + lh * 4);
        f32x4 q1 = *(const f32x4*)(pr + kt * 32 + 16 + lh * 4);
        s16x8 ah, al;
        split8(q0, q1, ah, al);
#pragma unroll
        for (int n0 = 0; n0 < 4; ++n0)
          C[m0][n0] = mm3(ah, al, Bh[kt][n0], Bl[kt][n0], C[m0][n0]);
      }
    }
    // e_new -> global + panel (after all stage-2 panel reads)
#pragma unroll
    for (int m0 = 0; m0 < 4; ++m0)
#pragma unroll
      for (int i = 0; i < 4; ++i)
#pragma unroll
        for (int n0 = 0; n0 < 4; ++n0) {
          float v = C[m0][n0][i];
          e_g[(size_t)(ebase + m0 * 16 + lh * 4 + i) * DD + n0 * 16 + lr] = v;
          T[(m0 * 16 + lh * 4 + i) * PST + n0 * 16 + lr] = v;
        }
    // ---------- stage 3: C = panel @ W1b ----------
#pragma unroll
    for (int kt = 0; kt < 2; ++kt)
#pragma unroll
      for (int n0 = 0; n0 < 4; ++n0) {
        Bh[kt][n0] = Wmat[2048 + (kt * 4 + n0) * 64 + lane];
        Bl[kt][n0] = Wmat[2048 + 512 + (kt * 4 + n0) * 64 + lane];
      }
#pragma unroll
    for (int m0 = 0; m0 < 4; ++m0) {
#pragma unroll
      for (int n0 = 0; n0 < 4; ++n0) C[m0][n0] = (f32x4){0.f, 0.f, 0.f, 0.f};
      const float* pr = T + (m0 * 16 + lr) * PST;
#pragma unroll
      for (int kt = 0; kt < 2; ++kt) {
        f32x4 q0 = *(const f32x4*)(pr + kt * 32 + lh * 4);
        f32x4 q1 = *(const f32x4*)(pr + kt * 32 + 16 + lh * 4);
        s16x8 ah, al;
        split8(q0, q1, ah, al);
#pragma unroll
        for (int n0 = 0; n0 < 4; ++n0)
          C[m0][n0] = mm3(ah, al, Bh[kt][n0], Bl[kt][n0], C[m0][n0]);
      }
    }
    // ---------- elementwise 2 -> panel ----------
#pragma unroll
    for (int m0 = 0; m0 < 4; ++m0)
#pragma unroll
      for (int i = 0; i < 4; ++i) {
        int r = row_g[ebase + m0 * 16 + lh * 4 + i];
        const float* hcr = Hc + (size_t)r * DD;
#pragma unroll
        for (int n0 = 0; n0 < 4; ++n0) {
          float v = C[m0][n0][i] + hcr[n0 * 16 + lr] + nb1f[n0];
          T[(m0 * 16 + lh * 4 + i) * PST + n0 * 16 + lr] = sp_f(v);
        }
      }
    // ---------- stage 4: C = panel @ nW2 + nb2 = msg ----------
#pragma unroll
    for (int kt = 0; kt < 2; ++kt)
#pragma unroll
      for (int n0 = 0; n0 < 4; ++n0) {
        Bh[kt][n0] = Wmat[3072 + (kt * 4 + n0) * 64 + lane];
        Bl[kt][n0] = Wmat[3072 + 512 + (kt * 4 + n0) * 64 + lane];
      }
#pragma unroll
    for (int m0 = 0; m0 < 4; ++m0) {
#pragma unroll
      for (int n0 = 0; n0 < 4; ++n0) C[m0][n0] = (f32x4){nb2f[n0], nb2f[n0], nb2f[n0], nb2f[n0]};
      const float* pr = T + (m0 * 16 + lr) * PST;
#pragma unroll
      for (int kt = 0; kt < 2; ++kt) {
        f32x4 q0 = *(const f32x4*)(pr + kt * 32 + lh * 4);
        f32x4 q1 = *(const f32x4*)(pr + kt * 32 + 16 + lh * 4);
        s16x8 ah, al;
        split8(q0, q1, ah, al);
#pragma unroll
        for (int n0 = 0; n0 < 4; ++n0)
          C[m0][n0] = mm3(ah, al, Bh[kt][n0], Bl[kt][n0], C[m0][n0]);
      }
    }
    // scatter-add messages
#pragma unroll
    for (int m0 = 0; m0 < 4; ++m0)
#pragma unroll
      for (int i = 0; i < 4; ++i) {
        int c = col_g[ebase + m0 * 16 + lh * 4 + i];
#pragma unroll
        for (int n0 = 0; n0 < 4; ++n0)
          atomicAdd(&hnew[(size_t)c * DD + n0 * 16 + lr], C[m0][n0][i]);
      }
  }
}

// per-channel sum & sumsq over h_new; optionally zero gsum/cnt (last layer)
__global__ __launch_bounds__(256)
void bn_stats_kernel(const float* __restrict__ hnew, float* __restrict__ stats,
                     float* __restrict__ gz) {
  int tid = blockIdx.x * 256 + threadIdx.x;
  if (gz) {
    for (int i = tid; i < GG * DD + GG; i += 128 * 256) gz[i] = 0.f;
  }
  int lane = threadIdx.x & 63, wid = threadIdx.x >> 6;
  int start = blockIdx.x * 4 + wid, step = gridDim.x * 4;
  float s = 0.f, q = 0.f;
  for (int n = start; n < N_ATOMS; n += step) {
    float v = hnew[(size_t)n * DD + lane];
    s += v;
    q = fmaf(v, v, q);
  }
  atomicAdd(&stats[lane], s);
  atomicAdd(&stats[DD + lane], q);
}

// h = sp(BN(h_new)) + h ; on last layer also pool into gsum/cnt
__global__ __launch_bounds__(256)
void bn_apply_kernel(const float* __restrict__ hnew, const float* __restrict__ stats,
                     const float* __restrict__ gamma, const float* __restrict__ beta,
                     float* __restrict__ h, const int* __restrict__ batch,
                     float* __restrict__ gsum, float* __restrict__ cnt) {
  int idx = blockIdx.x * 256 + threadIdx.x;
  int d = idx & 63;
  const float invN = 1.f / (float)N_ATOMS;
  float mu = stats[d] * invN;
  float var = fmaxf(stats[DD + d] * invN - mu * mu, 0.f);
  float inv = 1.f / sqrtf(var + 1e-5f);
  float hb = (hnew[idx] - mu) * inv * gamma[d] + beta[d];
  float hv = sp_f(hb) + h[idx];
  h[idx] = hv;
  if (batch) {
    int n = idx >> 6;
    int b = batch[n];
    atomicAdd(&gsum[(size_t)b * DD + d], hv);
    if (d == 0) atomicAdd(&cnt[b], 1.f);
  }
}

__global__ __launch_bounds__(128)
void pred_kernel(const float* __restrict__ gsum, const float* __restrict__ cnt,
                 const float* __restrict__ W1, const float* __restrict__ b1,
                 const float* __restrict__ W2, const float* __restrict__ b2,
                 const float* __restrict__ W3, const float* __restrict__ b3,
                 float* __restrict__ out) {
  __shared__ float sg[DD];
  __shared__ float so[HH];
  int g = blockIdx.x, t = threadIdx.x;
  if (t < DD) sg[t] = gsum[(size_t)g * DD + t] / fmaxf(cnt[g], 1.f);
  __syncthreads();
  float a = b1[t];
#pragma unroll
  for (int k = 0; k < DD; ++k) a = fmaf(sg[k], W1[k * HH + t], a);
  a = sp_f(a);
  so[t] = a;
  __syncthreads();
  float o = b2[t];
#pragma unroll
  for (int k = 0; k < HH; ++k) o = fmaf(so[k], W2[k * HH + t], o);
  o = sp_f(o);
  float contrib = o * W3[t];
  __syncthreads();
  so[t] = contrib;
  __syncthreads();
  if (t < 64) so[t] += so[t + 64];
  __syncthreads();
  if (t == 0) {
    float s = 0.f;
    for (int k = 0; k < 64; ++k) s += so[k];
    out[g] = s + b3[0];
  }
}

extern "C" void kernel_launch(void* const* d_in, const int* in_sizes, int n_in,
                              void* d_out, int out_size, void* d_ws, size_t ws_size,
                              hipStream_t stream) {
  const float* x         = (const float*)d_in[0];
  const float* edge_attr = (const float*)d_in[1];
  const int*   eidx      = (const int*)d_in[2];
  const int*   batch     = (const int*)d_in[3];
  const float* atom_W    = (const float*)d_in[4];
  const float* atom_b    = (const float*)d_in[5];
  const float* bond_W    = (const float*)d_in[6];
  const float* bond_b    = (const float*)d_in[7];
  const float* nu_W1     = (const float*)d_in[8];
  const float* nu_b1     = (const float*)d_in[9];
  const float* nu_W2     = (const float*)d_in[10];
  const float* nu_b2     = (const float*)d_in[11];
  const float* eu_W1     = (const float*)d_in[12];
  const float* eu_b1     = (const float*)d_in[13];
  const float* eu_W2     = (const float*)d_in[14];
  const float* eu_b2     = (const float*)d_in[15];
  const float* bn_gamma  = (const float*)d_in[16];
  const float* bn_beta   = (const float*)d_in[17];
  const float* pW1       = (const float*)d_in[18];
  const float* pb1       = (const float*)d_in[19];
  const float* pW2       = (const float*)d_in[20];
  const float* pb2       = (const float*)d_in[21];
  const float* pW3       = (const float*)d_in[22];
  const float* pb3       = (const float*)d_in[23];
  float* out = (float*)d_out;

  // workspace layout (float units)
  float* ws    = (float*)d_ws;
  float* h     = ws;                  // 3.2M
  float* hnew  = ws + 3200000;        // 3.2M
  float* Ha    = ws + 6400000;        // 3.2M
  float* Hb    = ws + 9600000;        // 3.2M
  float* Hc    = ws + 12800000;       // 3.2M
  float* stats = ws + 16000000;       // 128
  float* gsum  = ws + 16000128;       // 65536
  float* cnt   = ws + 16065664;       // 1024 (contiguous after gsum)
  short* wpack = (short*)(ws + 16066688); // 21 mats x 8192 shorts = 86016 floats
  float* e     = ws + 16152704;       // 76.8M

  const int* row = eidx;
  const int* col = eidx + N_EDGES;

  prep_pack_kernel<<<42, 256, 0, stream>>>(eu_W1, eu_W2, nu_W1, nu_W2, wpack);
  atom_embed_kernel<<<N_ATOMS / 16, 64, 0, stream>>>(x, atom_W, atom_b, h);
  bond_embed_kernel<<<N_EDGES / 16, 64, 0, stream>>>(edge_attr, bond_W, bond_b, e);

  for (int i = 0; i < LL; ++i) {
    node_pre_kernel<<<(NGROUP + 3) / 4, 256, 0, stream>>>(h, wpack, i, Ha, Hb, Hc, hnew, stats);
    edge_layer_kernel<<<512, 256, 0, stream>>>(
        Ha, Hb, Hc, e, row, col, wpack, i,
        eu_b1 + i * DD, eu_b2 + i * DD, nu_b1 + i * DD, nu_b2 + i * DD, hnew);
    bn_stats_kernel<<<128, 256, 0, stream>>>(hnew, stats,
                                             (i == LL - 1) ? gsum : (float*)nullptr);
    bn_apply_kernel<<<N_ATOMS * DD / 256, 256, 0, stream>>>(
        hnew, stats, bn_gamma + i * DD, bn_beta + i * DD, h,
        (i == LL - 1) ? batch : (const int*)nullptr, gsum, cnt);
  }

  pred_kernel<<<GG, 128, 0, stream>>>(gsum, cnt, pW1, pb1, pW2, pb2, pW3, pb3, out);
}